// Round 9
// baseline (344.135 us; speedup 1.0000x reference)
//
#include <hip/hip_runtime.h>
#include <stdint.h>

// MultiHeadAttention  b=4, L=2048, d=1024, H=16, dk=64. I/O fp32; bf16/f16 MFMA inside.
#define D_MODEL 1024
#define NHEADS 16
#define DKH 64
#define SEQ 2048
#define BATCH 4
#define M_TOT (BATCH * SEQ) // 8192
#define LOG2E 1.44269504088896340736f

typedef __bf16 v8bf __attribute__((ext_vector_type(8)));
typedef __bf16 v4bf __attribute__((ext_vector_type(4)));
typedef _Float16 v8h __attribute__((ext_vector_type(8)));
typedef _Float16 v4h __attribute__((ext_vector_type(4)));
typedef float v4f __attribute__((ext_vector_type(4)));
typedef float v16f __attribute__((ext_vector_type(16)));
typedef unsigned int v4u __attribute__((ext_vector_type(4)));
typedef unsigned int v2u __attribute__((ext_vector_type(2)));

typedef const __attribute__((address_space(1))) void* gas_ptr;
typedef __attribute__((address_space(3))) void* las_ptr;

static __device__ __forceinline__ void async16(const void* g, void* l) {
    __builtin_amdgcn_global_load_lds((gas_ptr)g, (las_ptr)l, 16, 0, 0);
}

static __device__ __forceinline__ v4f mfma16x32(v8bf a, v8bf b, v4f c) {
    // D(16x16)=A(16x32)*B(32x16)+C. A: m=l&15,k=(l>>4)*8+j. B: k=(l>>4)*8+j,n=l&15.
    // D: col=l&15, row=(l>>4)*4+reg.
    return __builtin_amdgcn_mfma_f32_16x16x32_bf16(a, b, c, 0, 0, 0);
}
static __device__ __forceinline__ v16f mfma32x16bf(v8bf a, v8bf b, v16f c) {
    // D(32x32)=A(32x16)*B(16x32)+C. A: m=l&31,k=(l>>5)*8+j. B: k=(l>>5)*8+j,n=l&31.
    // D: col=l&31, row=(reg&3)+8*(reg>>2)+4*(l>>5).
    return __builtin_amdgcn_mfma_f32_32x32x16_bf16(a, b, c, 0, 0, 0);
}
static __device__ __forceinline__ v16f mfma32x16h(v8h a, v8h b, v16f c) {
    return __builtin_amdgcn_mfma_f32_32x32x16_f16(a, b, c, 0, 0, 0);
}
static __device__ __forceinline__ unsigned pkh(float a, float b) {
    // v_cvt_pkrtz_f16_f32: packs two f32 -> two f16 in one u32
    return __builtin_bit_cast(unsigned, __builtin_amdgcn_cvt_pkrtz(a, b));
}
// swap lane i <-> lane i^32 contents of x/y: returns {new_x, new_y}
static __device__ __forceinline__ void plswap(unsigned& x, unsigned& y) {
    v2u r = __builtin_amdgcn_permlane32_swap(x, y, false, false);
    x = r[0];
    y = r[1];
}
// raw v_exp_f32 (single instruction; no denormal-guard expansion).
static __device__ __forceinline__ float fexp2(float x) {
#if __has_builtin(__builtin_amdgcn_exp2f)
    return __builtin_amdgcn_exp2f(x);
#else
    float r;
    asm("v_exp_f32 %0, %1" : "=v"(r) : "v"(x));
    return r;
#endif
}

// fp32 -> bf16, 8 elements/thread (serial-fallback path)
__global__ __launch_bounds__(256) void cvt_x(const float* __restrict__ src,
                                             __bf16* __restrict__ dst) {
    int i = blockIdx.x * 256 + threadIdx.x;
    const float4* s = (const float4*)src;
    float4 a = s[2 * i], b = s[2 * i + 1];
    v8bf o;
    o[0] = (__bf16)a.x; o[1] = (__bf16)a.y; o[2] = (__bf16)a.z; o[3] = (__bf16)a.w;
    o[4] = (__bf16)b.x; o[5] = (__bf16)b.y; o[6] = (__bf16)b.z; o[7] = (__bf16)b.w;
    *(v8bf*)(dst + (size_t)i * 8) = o;
}

// Convert 4 fp32 weight matrices to packed bf16 [4][1024*1024] (serial fallback)
__global__ __launch_bounds__(256) void cvt_w(const float* __restrict__ w0,
                                             const float* __restrict__ w1,
                                             const float* __restrict__ w2,
                                             const float* __restrict__ w3,
                                             __bf16* __restrict__ dst) {
    int gid = blockIdx.x * 256 + threadIdx.x;
    int tsel = gid >> 17;
    int off = gid & 131071;
    const float* s = (tsel == 0) ? w0 : (tsel == 1) ? w1 : (tsel == 2) ? w2 : w3;
    const float4* sp = (const float4*)s + 2 * (size_t)off;
    float4 a = sp[0], b = sp[1];
    v8bf o;
    o[0] = (__bf16)a.x; o[1] = (__bf16)a.y; o[2] = (__bf16)a.z; o[3] = (__bf16)a.w;
    o[4] = (__bf16)b.x; o[5] = (__bf16)b.y; o[6] = (__bf16)b.z; o[7] = (__bf16)b.w;
    *(v8bf*)(dst + ((size_t)tsel << 20) + (size_t)off * 8) = o;
}

// Single prep kernel: weights (blocks [0,2048)) + Q/K/V activations (blocks
// [2048,14336)) in one launch — removes one stream-serialization gap.
__global__ __launch_bounds__(256) void cvt_all(const float* __restrict__ Q,
                                               const float* __restrict__ K,
                                               const float* __restrict__ V,
                                               const float* __restrict__ w0,
                                               const float* __restrict__ w1,
                                               const float* __restrict__ w2,
                                               const float* __restrict__ w3,
                                               __bf16* __restrict__ xq,
                                               __bf16* __restrict__ xk,
                                               __bf16* __restrict__ xv,
                                               __bf16* __restrict__ wb) {
    const int blk = blockIdx.x;
    const float* src;
    __bf16* dst;
    size_t off8;
    if (blk < 2048) {
        int gid = blk * 256 + threadIdx.x;
        int tsel = gid >> 17;
        src = (tsel == 0) ? w0 : (tsel == 1) ? w1 : (tsel == 2) ? w2 : w3;
        dst = wb + ((size_t)tsel << 20);
        off8 = (size_t)(gid & 131071);
    } else {
        int gb = blk - 2048;
        int t = gb >> 12; // 4096 blocks per tensor
        src = (t == 0) ? Q : (t == 1) ? K : V;
        dst = (t == 0) ? xq : (t == 1) ? xk : xv;
        off8 = (size_t)((gb & 4095) * 256 + threadIdx.x);
    }
    const float4* sp = (const float4*)src + 2 * off8;
    float4 a = sp[0], b = sp[1];
    v8bf o;
    o[0] = (__bf16)a.x; o[1] = (__bf16)a.y; o[2] = (__bf16)a.z; o[3] = (__bf16)a.w;
    o[4] = (__bf16)b.x; o[5] = (__bf16)b.y; o[6] = (__bf16)b.z; o[7] = (__bf16)b.w;
    *(v8bf*)(dst + off8 * 8) = o;
}

// ---- shared GEMM K-loop body (2-phase, counted vmcnt) -----------------------
#define GEMM_KLOOP(Abase, Wbase)                                                   \
    auto stage = [&](int bi, int k0) {                                             \
        _Pragma("unroll") for (int p = 0; p < 2; ++p) {                            \
            int rb = (p * 4 + wave) * 16;                                          \
            async16(Abase + (size_t)(rb + wrow) * D_MODEL + k0, &As[bi][rb * 32]); \
            async16(Wbase + (size_t)(rb + wrow) * D_MODEL + k0, &Bs[bi][rb * 32]); \
        }                                                                          \
    };                                                                             \
    stage(0, 0);                                                                   \
    for (int it = 0; it < D_MODEL / 32; ++it) {                                    \
        const int cur = it & 1;                                                    \
        if (it + 1 < D_MODEL / 32) {                                               \
            stage(cur ^ 1, (it + 1) * 32);                                         \
            asm volatile("s_waitcnt vmcnt(4)" ::: "memory");                       \
        } else {                                                                   \
            asm volatile("s_waitcnt vmcnt(0)" ::: "memory");                       \
        }                                                                          \
        __builtin_amdgcn_s_barrier();                                              \
        __builtin_amdgcn_sched_barrier(0);                                         \
        v8bf af[4], bfr[4];                                                        \
        _Pragma("unroll") for (int mt = 0; mt < 4; ++mt)                           \
            af[mt] = *(const v8bf*)&As[cur][(mw + mt * 16 + r) * 32 + rdpos];      \
        _Pragma("unroll") for (int nt = 0; nt < 4; ++nt)                           \
            bfr[nt] = *(const v8bf*)&Bs[cur][(nw + nt * 16 + r) * 32 + rdpos];     \
        _Pragma("unroll") for (int mt = 0; mt < 4; ++mt)                           \
            _Pragma("unroll") for (int nt = 0; nt < 4; ++nt)                       \
                acc[mt][nt] = mfma16x32(af[mt], bfr[nt], acc[mt][nt]);             \
        asm volatile("s_waitcnt lgkmcnt(0)" ::: "memory");                         \
        __builtin_amdgcn_s_barrier();                                              \
    }

// m97-style NT GEMM: C = scale * A.W^T. 128x128 tile, BK=32, 2-phase prefetch.
template <int LAYOUT>
__global__ __launch_bounds__(256) void gemm_nt(const __bf16* __restrict__ A,
                                               const __bf16* __restrict__ W,
                                               void* __restrict__ Cv, float scale) {
    const int t = threadIdx.x, lane = t & 63, wave = t >> 6;
    const int r = lane & 15, qd = lane >> 4;
    const int m0 = blockIdx.x * 128, n0 = blockIdx.y * 128;
    const int mw = (wave & 1) * 64, nw = (wave >> 1) * 64;

    __shared__ __align__(16) __bf16 As[2][128 * 32];
    __shared__ __align__(16) __bf16 Bs[2][128 * 32];

    const int wc = (lane & 3) ^ ((lane >> 3) & 3);
    const int wrow = lane >> 2;
    const int rdpos = (qd ^ ((r >> 1) & 3)) * 8;

    const __bf16* Ab = A + (size_t)m0 * D_MODEL + wc * 8;
    const __bf16* Wb = W + (size_t)n0 * D_MODEL + wc * 8;

    v4f acc[4][4] = {};
    GEMM_KLOOP(Ab, Wb)

#pragma unroll
    for (int mt = 0; mt < 4; ++mt)
#pragma unroll
        for (int nt = 0; nt < 4; ++nt) {
            int row = m0 + mw + mt * 16 + qd * 4;
            int col = n0 + nw + nt * 16 + r;
            if (LAYOUT == 0) {
                float* C = (float*)Cv;
#pragma unroll
                for (int i = 0; i < 4; ++i)
                    C[(size_t)(row + i) * D_MODEL + col] = acc[mt][nt][i];
            } else {
                int bb = row >> 11, l = row & (SEQ - 1);
                int h = col >> 6, d = col & (DKH - 1);
                if (LAYOUT == 2) {
                    _Float16* vt = (_Float16*)Cv;
                    v4h o;
#pragma unroll
                    for (int i = 0; i < 4; ++i) o[i] = (_Float16)acc[mt][nt][i];
                    *(v4h*)&vt[((size_t)((bb * NHEADS + h) * DKH + d)) * SEQ + l] = o;
                } else {
                    __bf16* dst = (__bf16*)Cv;
#pragma unroll
                    for (int i = 0; i < 4; ++i)
                        dst[(((size_t)(bb * NHEADS + h) * SEQ) + l + i) * DKH + d] =
                            (__bf16)(acc[mt][nt][i] * scale);
                }
            }
        }
}

// Fused QKV projection: gridDim.z = 3 selects {Q,K,V}; 1536 blocks -> deep TLP.
__global__ __launch_bounds__(256) void gemm_qkv(const __bf16* __restrict__ xq,
                                                const __bf16* __restrict__ xk,
                                                const __bf16* __restrict__ xv,
                                                const __bf16* __restrict__ wb,
                                                __bf16* __restrict__ qh,
                                                __bf16* __restrict__ kh,
                                                _Float16* __restrict__ vtb, float qs) {
    const int z = blockIdx.z;
    const __bf16* A = (z == 0) ? xq : (z == 1) ? xk : xv;
    const __bf16* W = wb + (size_t)z * D_MODEL * D_MODEL;

    const int t = threadIdx.x, lane = t & 63, wave = t >> 6;
    const int r = lane & 15, qd = lane >> 4;
    const int m0 = blockIdx.x * 128, n0 = blockIdx.y * 128;
    const int mw = (wave & 1) * 64, nw = (wave >> 1) * 64;

    __shared__ __align__(16) __bf16 As[2][128 * 32];
    __shared__ __align__(16) __bf16 Bs[2][128 * 32];

    const int wc = (lane & 3) ^ ((lane >> 3) & 3);
    const int wrow = lane >> 2;
    const int rdpos = (qd ^ ((r >> 1) & 3)) * 8;

    const __bf16* Ab = A + (size_t)m0 * D_MODEL + wc * 8;
    const __bf16* Wb = W + (size_t)n0 * D_MODEL + wc * 8;

    v4f acc[4][4] = {};
    GEMM_KLOOP(Ab, Wb)

    const float scale = (z == 0) ? qs : 1.0f;
#pragma unroll
    for (int mt = 0; mt < 4; ++mt)
#pragma unroll
        for (int nt = 0; nt < 4; ++nt) {
            int row = m0 + mw + mt * 16 + qd * 4;
            int col = n0 + nw + nt * 16 + r;
            int bb = row >> 11, l = row & (SEQ - 1);
            int h = col >> 6, d = col & (DKH - 1);
            if (z == 2) {
                v4h o;
#pragma unroll
                for (int i = 0; i < 4; ++i) o[i] = (_Float16)acc[mt][nt][i];
                *(v4h*)&vtb[((size_t)((bb * NHEADS + h) * DKH + d)) * SEQ + l] = o;
            } else {
                __bf16* dst = (z == 0) ? qh : kh;
#pragma unroll
                for (int i = 0; i < 4; ++i)
                    dst[(((size_t)(bb * NHEADS + h) * SEQ) + l + i) * DKH + d] =
                        (__bf16)(acc[mt][nt][i] * scale);
            }
        }
}

// Attention, 32-query-per-wave version: 1024 blocks (4/CU, 4 waves/SIMD —
// double the TLP of the 64q/wave layout whose 2048 total waves pinned
// occupancy at 2/SIMD). Each wave: 32 queries x all 64 dk; K/V staged in
// double-buffered 64-key LDS tiles by all 4 waves. QK: 4x mfma_32x32x16_bf16;
// P via raw v_exp_f32 + cvt_pkrtz + permlane32_swap; PV: 4x mfma_32x32x16_f16.
__global__ __launch_bounds__(256, 2) void attn_kernel(const __bf16* __restrict__ qh,
                                                      const __bf16* __restrict__ kh,
                                                      const _Float16* __restrict__ vt,
                                                      __bf16* __restrict__ oh) {
    const int lane = threadIdx.x & 63, wave = threadIdx.x >> 6;
    const int l31 = lane & 31, hi = lane >> 5, l7 = lane & 7;
    const int id = blockIdx.x;
    const int bh = (id & 7) * 8 + ((id >> 3) & 7); // 8 bh per XCD
    const int q0 = (id >> 6) * 128 + wave * 32;    // 16 q-chunks of 128 per bh

    __shared__ __align__(16) __bf16 Kb[2][64 * 64];
    __shared__ __align__(16) _Float16 Vb[2][64 * 64];

    const __bf16* kbh = kh + (size_t)bh * SEQ * DKH;
    const _Float16* vbh = vt + (size_t)bh * DKH * SEQ;

    // Q B-frags: query n = q0 + l31, k = c*16 + hi*8 + j
    v8bf qf[4];
#pragma unroll
    for (int c = 0; c < 4; ++c)
        qf[c] = *(const v8bf*)&qh[((size_t)bh * SEQ + q0 + l31) * DKH + c * 16 + hi * 8];

    v16f oacc[2] = {};
    float ps = 0.f;
    const v16f dz = {};

    // staging map: wave covers rows wave*16..+15 in 2 passes of 8 rows; 128B rows,
    // dest linear, source chunk XOR-swizzled: LDS chunk p of row rho = src chunk p^(rho&7)
    const int srow = lane >> 3;
    const int sc = (lane & 7) ^ srow;

#pragma unroll
    for (int p = 0; p < 2; ++p) {
        int rb = wave * 16 + p * 8;
        async16(kbh + (size_t)(rb + srow) * DKH + sc * 8, &Kb[0][rb * 64]);
        async16(vbh + (size_t)(rb + srow) * SEQ + sc * 8, &Vb[0][rb * 64]);
    }

    for (int tt = 0; tt < SEQ / 64; ++tt) {
        const int buf = tt & 1;
        __syncthreads(); // buf staged; all waves done reading buf^1
        if (tt + 1 < SEQ / 64) {
            const int t0 = (tt + 1) * 64;
#pragma unroll
            for (int p = 0; p < 2; ++p) {
                int rb = wave * 16 + p * 8;
                async16(kbh + (size_t)(t0 + rb + srow) * DKH + sc * 8, &Kb[buf ^ 1][rb * 64]);
                async16(vbh + (size_t)(rb + srow) * SEQ + t0 + sc * 8, &Vb[buf ^ 1][rb * 64]);
            }
        }
        const __bf16* Kc = Kb[buf];
        const _Float16* Vc = Vb[buf];
#pragma unroll
        for (int kb = 0; kb < 2; ++kb) {
            // K A-frags: m = kb*32 + l31 (key), k = c*16 + hi*8 + j (dk)
            v8bf ka[4];
#pragma unroll
            for (int c = 0; c < 4; ++c)
                ka[c] = *(const v8bf*)&Kc[(kb * 32 + l31) * 64 + (((c * 2 + hi) ^ l7) << 3)];
            v16f d = mfma32x16bf(ka[0], qf[0], dz);
#pragma unroll
            for (int c = 1; c < 4; ++c) d = mfma32x16bf(ka[c], qf[c], d);
            // d reg r = S[key kb*32 + (r&3)+8*(r>>2)+4*hi][query q0+l31]
            float e[16];
#pragma unroll
            for (int i = 0; i < 16; ++i) e[i] = fexp2(d[i]);
            ps += (((e[0] + e[1]) + (e[2] + e[3])) + ((e[4] + e[5]) + (e[6] + e[7]))) +
                  (((e[8] + e[9]) + (e[10] + e[11])) + ((e[12] + e[13]) + (e[14] + e[15])));
            v8h pb[2]; // [16-key half]
#pragma unroll
            for (int kc = 0; kc < 2; ++kc) {
                // keys kb*32 + kc*16 + {0..15}; own: {0-3,8-11}+4hi, partner: rest
                unsigned a0 = pkh(e[kc * 8 + 0], e[kc * 8 + 1]); // keys {0,1}+4hi
                unsigned a1 = pkh(e[kc * 8 + 2], e[kc * 8 + 3]); // keys {2,3}+4hi
                unsigned b0 = pkh(e[kc * 8 + 4], e[kc * 8 + 5]); // keys {8,9}+4hi
                unsigned b1 = pkh(e[kc * 8 + 6], e[kc * 8 + 7]); // keys {10,11}+4hi
                // after swap: a0'=[own lo, partner lo] = k j={0,1}; b0'=k j={4,5}; etc.
                plswap(a0, b0);
                plswap(a1, b1);
                v4u w = {a0, a1, b0, b1};
                pb[kc] = __builtin_bit_cast(v8h, w);
            }
#pragma unroll
            for (int dg = 0; dg < 2; ++dg)
#pragma unroll
                for (int kc = 0; kc < 2; ++kc) {
                    // V^T A-frag: m = dg*32 + l31 (dk), k = keys kb*32+kc*16+hi*8+j
                    v8h va = *(const v8h*)&Vc[(dg * 32 + l31) * 64 +
                                              (((kb * 4 + kc * 2 + hi) ^ l7) << 3)];
                    oacc[dg] = mfma32x16h(va, pb[kc], oacc[dg]);
                }
        }
    }

    const int b = bh >> 4, h = bh & (NHEADS - 1);
    float tot = ps + __shfl_xor(ps, 32, 64); // partner covers other 16-key halves
    float inv = 1.0f / tot;
    int lq = q0 + l31;
    __bf16* op = oh + (((size_t)(b * SEQ + lq)) * NHEADS + h) * DKH;
#pragma unroll
    for (int dg = 0; dg < 2; ++dg)
#pragma unroll
        for (int g = 0; g < 4; ++g) {
            // oacc reg 4g+i -> dk = dg*32 + g*8 + hi*4 + i
            v4bf ov;
#pragma unroll
            for (int i = 0; i < 4; ++i) ov[i] = (__bf16)(oacc[dg][g * 4 + i] * inv);
            *(v4bf*)(op + dg * 32 + g * 8 + hi * 4) = ov;
        }
}

extern "C" void kernel_launch(void* const* d_in, const int* in_sizes, int n_in,
                              void* d_out, int out_size, void* d_ws, size_t ws_size,
                              hipStream_t stream) {
    const float* Q = (const float*)d_in[0];
    const float* K = (const float*)d_in[1];
    const float* V = (const float*)d_in[2];
    const float* WQ = (const float*)d_in[3];
    const float* WK = (const float*)d_in[4];
    const float* WV = (const float*)d_in[5];
    const float* WO = (const float*)d_in[6];
    float* out = (float*)d_out;

    const size_t elems = (size_t)M_TOT * D_MODEL;    // 8.4M
    const size_t welems = (size_t)D_MODEL * D_MODEL; // 1.05M
    const size_t fused_need = 8 * welems + 6 * 2 * elems; // bytes: wb(8MB)+6x16MB = 104MB

    dim3 gg(M_TOT / 128, D_MODEL / 128);

    if (ws_size >= fused_need) {
        // Fused path: wb | xq | xk | xv | qh | kh | vtb ; oh aliases xq (dead
        // after gemm_qkv completes; attn writes oh strictly after).
        __bf16* wb = (__bf16*)d_ws;
        __bf16* xq = wb + 4 * welems;
        __bf16* xk = xq + elems;
        __bf16* xv = xk + elems;
        __bf16* qh = xv + elems;
        __bf16* kh = qh + elems;
        _Float16* vtb = (_Float16*)(kh + elems);
        __bf16* oh = xq; // alias

        cvt_all<<<14336, 256, 0, stream>>>(Q, K, V, WQ, WK, WV, WO, xq, xk, xv, wb);
        dim3 gz(M_TOT / 128, D_MODEL / 128, 3);
        gemm_qkv<<<gz, 256, 0, stream>>>(xq, xk, xv, wb, qh, kh, vtb, 0.125f * LOG2E);
        attn_kernel<<<1024, 256, 0, stream>>>(qh, kh, vtb, oh);
        gemm_nt<0><<<gg, 256, 0, stream>>>(oh, wb + 3 * welems, out, 1.0f);
    } else {
        // Serial fallback (88 MB).
        __bf16* wb = (__bf16*)d_ws;
        __bf16* xb = wb + 4 * welems;
        __bf16* qh = xb + elems;
        __bf16* kh = qh + elems;
        _Float16* vtb = (_Float16*)(kh + elems);
        __bf16* oh = (__bf16*)(vtb + elems);

        cvt_w<<<2048, 256, 0, stream>>>(WQ, WK, WV, WO, wb);
        cvt_x<<<4096, 256, 0, stream>>>(Q, xb);
        gemm_nt<1><<<gg, 256, 0, stream>>>(xb, wb, qh, 0.125f * LOG2E);
        cvt_x<<<4096, 256, 0, stream>>>(K, xb);
        gemm_nt<1><<<gg, 256, 0, stream>>>(xb, wb + welems, kh, 1.0f);
        cvt_x<<<4096, 256, 0, stream>>>(V, xb);
        gemm_nt<2><<<gg, 256, 0, stream>>>(xb, wb + 2 * welems, vtb, 1.0f);
        attn_kernel<<<1024, 256, 0, stream>>>(qh, kh, vtb, oh);
        gemm_nt<0><<<gg, 256, 0, stream>>>(oh, wb + 3 * welems, out, 1.0f);
    }
}

// Round 12
// 317.901 us; speedup vs baseline: 1.0825x; 1.0825x over previous
//
#include <hip/hip_runtime.h>
#include <stdint.h>

// MultiHeadAttention  b=4, L=2048, d=1024, H=16, dk=64. I/O fp32; bf16/f16 MFMA inside.
#define D_MODEL 1024
#define NHEADS 16
#define DKH 64
#define SEQ 2048
#define BATCH 4
#define M_TOT (BATCH * SEQ) // 8192
#define LOG2E 1.44269504088896340736f

typedef __bf16 v8bf __attribute__((ext_vector_type(8)));
typedef __bf16 v4bf __attribute__((ext_vector_type(4)));
typedef _Float16 v8h __attribute__((ext_vector_type(8)));
typedef _Float16 v4h __attribute__((ext_vector_type(4)));
typedef float v4f __attribute__((ext_vector_type(4)));
typedef float v16f __attribute__((ext_vector_type(16)));
typedef unsigned int v4u __attribute__((ext_vector_type(4)));
typedef unsigned int v2u __attribute__((ext_vector_type(2)));

typedef const __attribute__((address_space(1))) void* gas_ptr;
typedef __attribute__((address_space(3))) void* las_ptr;

static __device__ __forceinline__ void async16(const void* g, void* l) {
    __builtin_amdgcn_global_load_lds((gas_ptr)g, (las_ptr)l, 16, 0, 0);
}

static __device__ __forceinline__ v4f mfma16x32(v8bf a, v8bf b, v4f c) {
    // D(16x16)=A(16x32)*B(32x16)+C. A: m=l&15,k=(l>>4)*8+j. B: k=(l>>4)*8+j,n=l&15.
    // D: col=l&15, row=(l>>4)*4+reg.
    return __builtin_amdgcn_mfma_f32_16x16x32_bf16(a, b, c, 0, 0, 0);
}
static __device__ __forceinline__ v16f mfma32x16bf(v8bf a, v8bf b, v16f c) {
    // D(32x32)=A(32x16)*B(16x32)+C. A: m=l&31,k=(l>>5)*8+j. B: k=(l>>5)*8+j,n=l&31.
    // D: col=l&31, row=(reg&3)+8*(reg>>2)+4*(l>>5).
    return __builtin_amdgcn_mfma_f32_32x32x16_bf16(a, b, c, 0, 0, 0);
}
static __device__ __forceinline__ v16f mfma32x16h(v8h a, v8h b, v16f c) {
    return __builtin_amdgcn_mfma_f32_32x32x16_f16(a, b, c, 0, 0, 0);
}
static __device__ __forceinline__ unsigned pkh(float a, float b) {
    // v_cvt_pkrtz_f16_f32: packs two f32 -> two f16 in one u32
    return __builtin_bit_cast(unsigned, __builtin_amdgcn_cvt_pkrtz(a, b));
}
// swap lane i <-> lane i^32 contents of x/y: returns {new_x, new_y}
static __device__ __forceinline__ void plswap(unsigned& x, unsigned& y) {
    v2u r = __builtin_amdgcn_permlane32_swap(x, y, false, false);
    x = r[0];
    y = r[1];
}
// raw v_exp_f32 (single instruction; no denormal-guard expansion).
static __device__ __forceinline__ float fexp2(float x) {
#if __has_builtin(__builtin_amdgcn_exp2f)
    return __builtin_amdgcn_exp2f(x);
#else
    float r;
    asm("v_exp_f32 %0, %1" : "=v"(r) : "v"(x));
    return r;
#endif
}

// fp32 -> bf16, 8 elements/thread (serial-fallback path)
__global__ __launch_bounds__(256) void cvt_x(const float* __restrict__ src,
                                             __bf16* __restrict__ dst) {
    int i = blockIdx.x * 256 + threadIdx.x;
    const float4* s = (const float4*)src;
    float4 a = s[2 * i], b = s[2 * i + 1];
    v8bf o;
    o[0] = (__bf16)a.x; o[1] = (__bf16)a.y; o[2] = (__bf16)a.z; o[3] = (__bf16)a.w;
    o[4] = (__bf16)b.x; o[5] = (__bf16)b.y; o[6] = (__bf16)b.z; o[7] = (__bf16)b.w;
    *(v8bf*)(dst + (size_t)i * 8) = o;
}

// Convert 4 fp32 weight matrices to packed bf16 [4][1024*1024] (serial fallback)
__global__ __launch_bounds__(256) void cvt_w(const float* __restrict__ w0,
                                             const float* __restrict__ w1,
                                             const float* __restrict__ w2,
                                             const float* __restrict__ w3,
                                             __bf16* __restrict__ dst) {
    int gid = blockIdx.x * 256 + threadIdx.x;
    int tsel = gid >> 17;
    int off = gid & 131071;
    const float* s = (tsel == 0) ? w0 : (tsel == 1) ? w1 : (tsel == 2) ? w2 : w3;
    const float4* sp = (const float4*)s + 2 * (size_t)off;
    float4 a = sp[0], b = sp[1];
    v8bf o;
    o[0] = (__bf16)a.x; o[1] = (__bf16)a.y; o[2] = (__bf16)a.z; o[3] = (__bf16)a.w;
    o[4] = (__bf16)b.x; o[5] = (__bf16)b.y; o[6] = (__bf16)b.z; o[7] = (__bf16)b.w;
    *(v8bf*)(dst + ((size_t)tsel << 20) + (size_t)off * 8) = o;
}

// Single prep kernel: weights (blocks [0,2048)) + Q/K/V activations (blocks
// [2048,14336)) in one launch — removes one stream-serialization gap.
__global__ __launch_bounds__(256) void cvt_all(const float* __restrict__ Q,
                                               const float* __restrict__ K,
                                               const float* __restrict__ V,
                                               const float* __restrict__ w0,
                                               const float* __restrict__ w1,
                                               const float* __restrict__ w2,
                                               const float* __restrict__ w3,
                                               __bf16* __restrict__ xq,
                                               __bf16* __restrict__ xk,
                                               __bf16* __restrict__ xv,
                                               __bf16* __restrict__ wb) {
    const int blk = blockIdx.x;
    const float* src;
    __bf16* dst;
    size_t off8;
    if (blk < 2048) {
        int gid = blk * 256 + threadIdx.x;
        int tsel = gid >> 17;
        src = (tsel == 0) ? w0 : (tsel == 1) ? w1 : (tsel == 2) ? w2 : w3;
        dst = wb + ((size_t)tsel << 20);
        off8 = (size_t)(gid & 131071);
    } else {
        int gb = blk - 2048;
        int t = gb >> 12; // 4096 blocks per tensor
        src = (t == 0) ? Q : (t == 1) ? K : V;
        dst = (t == 0) ? xq : (t == 1) ? xk : xv;
        off8 = (size_t)((gb & 4095) * 256 + threadIdx.x);
    }
    const float4* sp = (const float4*)src + 2 * off8;
    float4 a = sp[0], b = sp[1];
    v8bf o;
    o[0] = (__bf16)a.x; o[1] = (__bf16)a.y; o[2] = (__bf16)a.z; o[3] = (__bf16)a.w;
    o[4] = (__bf16)b.x; o[5] = (__bf16)b.y; o[6] = (__bf16)b.z; o[7] = (__bf16)b.w;
    *(v8bf*)(dst + off8 * 8) = o;
}

// ---- shared GEMM K-loop body: 3-deep LDS rotation, ONE barrier per K-step ---
// Buffer it%3 is read in iter it and overwritten by the stage issued in iter
// it+2; barrier drift is bounded to <1 segment by the single barrier, so no
// trailing lgkmcnt-barrier is needed. stage -> vmcnt(4) -> barrier guarantees
// every wave's async16 writes for cur have landed before any wave reads cur.
#define GEMM_KLOOP(Abase, Wbase)                                                   \
    auto stage = [&](int bi, int k0) {                                             \
        _Pragma("unroll") for (int p = 0; p < 2; ++p) {                            \
            int rb = (p * 4 + wave) * 16;                                          \
            async16(Abase + (size_t)(rb + wrow) * D_MODEL + k0, &As[bi][rb * 32]); \
            async16(Wbase + (size_t)(rb + wrow) * D_MODEL + k0, &Bs[bi][rb * 32]); \
        }                                                                          \
    };                                                                             \
    stage(0, 0);                                                                   \
    for (int it = 0; it < D_MODEL / 32; ++it) {                                    \
        const int cur = it % 3;                                                    \
        if (it + 1 < D_MODEL / 32) {                                               \
            stage((it + 1) % 3, (it + 1) * 32);                                    \
            asm volatile("s_waitcnt vmcnt(4)" ::: "memory");                       \
        } else {                                                                   \
            asm volatile("s_waitcnt vmcnt(0)" ::: "memory");                       \
        }                                                                          \
        __builtin_amdgcn_s_barrier();                                              \
        __builtin_amdgcn_sched_barrier(0);                                         \
        v8bf af[4], bfr[4];                                                        \
        _Pragma("unroll") for (int mt = 0; mt < 4; ++mt)                           \
            af[mt] = *(const v8bf*)&As[cur][(mw + mt * 16 + r) * 32 + rdpos];      \
        _Pragma("unroll") for (int nt = 0; nt < 4; ++nt)                           \
            bfr[nt] = *(const v8bf*)&Bs[cur][(nw + nt * 16 + r) * 32 + rdpos];     \
        _Pragma("unroll") for (int mt = 0; mt < 4; ++mt)                           \
            _Pragma("unroll") for (int nt = 0; nt < 4; ++nt)                       \
                acc[mt][nt] = mfma16x32(af[mt], bfr[nt], acc[mt][nt]);             \
    }

// m97-style NT GEMM: C = scale * A.W^T. 128x128 tile, BK=32, 3-buffer rotation.
template <int LAYOUT>
__global__ __launch_bounds__(256) void gemm_nt(const __bf16* __restrict__ A,
                                               const __bf16* __restrict__ W,
                                               void* __restrict__ Cv, float scale) {
    const int t = threadIdx.x, lane = t & 63, wave = t >> 6;
    const int r = lane & 15, qd = lane >> 4;
    const int m0 = blockIdx.x * 128, n0 = blockIdx.y * 128;
    const int mw = (wave & 1) * 64, nw = (wave >> 1) * 64;

    __shared__ __align__(16) __bf16 As[3][128 * 32];
    __shared__ __align__(16) __bf16 Bs[3][128 * 32];

    const int wc = (lane & 3) ^ ((lane >> 3) & 3);
    const int wrow = lane >> 2;
    const int rdpos = (qd ^ ((r >> 1) & 3)) * 8;

    const __bf16* Ab = A + (size_t)m0 * D_MODEL + wc * 8;
    const __bf16* Wb = W + (size_t)n0 * D_MODEL + wc * 8;

    v4f acc[4][4] = {};
    GEMM_KLOOP(Ab, Wb)

#pragma unroll
    for (int mt = 0; mt < 4; ++mt)
#pragma unroll
        for (int nt = 0; nt < 4; ++nt) {
            int row = m0 + mw + mt * 16 + qd * 4;
            int col = n0 + nw + nt * 16 + r;
            if (LAYOUT == 0) {
                float* C = (float*)Cv;
#pragma unroll
                for (int i = 0; i < 4; ++i)
                    C[(size_t)(row + i) * D_MODEL + col] = acc[mt][nt][i];
            } else {
                int bb = row >> 11, l = row & (SEQ - 1);
                int h = col >> 6, d = col & (DKH - 1);
                if (LAYOUT == 2) {
                    _Float16* vt = (_Float16*)Cv;
                    v4h o;
#pragma unroll
                    for (int i = 0; i < 4; ++i) o[i] = (_Float16)acc[mt][nt][i];
                    *(v4h*)&vt[((size_t)((bb * NHEADS + h) * DKH + d)) * SEQ + l] = o;
                } else {
                    __bf16* dst = (__bf16*)Cv;
#pragma unroll
                    for (int i = 0; i < 4; ++i)
                        dst[(((size_t)(bb * NHEADS + h) * SEQ) + l + i) * DKH + d] =
                            (__bf16)(acc[mt][nt][i] * scale);
                }
            }
        }
}

// Fused QKV projection: gridDim.z = 3 selects {Q,K,V}; 1536 blocks -> deep TLP.
__global__ __launch_bounds__(256) void gemm_qkv(const __bf16* __restrict__ xq,
                                                const __bf16* __restrict__ xk,
                                                const __bf16* __restrict__ xv,
                                                const __bf16* __restrict__ wb,
                                                __bf16* __restrict__ qh,
                                                __bf16* __restrict__ kh,
                                                _Float16* __restrict__ vtb, float qs) {
    const int z = blockIdx.z;
    const __bf16* A = (z == 0) ? xq : (z == 1) ? xk : xv;
    const __bf16* W = wb + (size_t)z * D_MODEL * D_MODEL;

    const int t = threadIdx.x, lane = t & 63, wave = t >> 6;
    const int r = lane & 15, qd = lane >> 4;
    const int m0 = blockIdx.x * 128, n0 = blockIdx.y * 128;
    const int mw = (wave & 1) * 64, nw = (wave >> 1) * 64;

    __shared__ __align__(16) __bf16 As[3][128 * 32];
    __shared__ __align__(16) __bf16 Bs[3][128 * 32];

    const int wc = (lane & 3) ^ ((lane >> 3) & 3);
    const int wrow = lane >> 2;
    const int rdpos = (qd ^ ((r >> 1) & 3)) * 8;

    const __bf16* Ab = A + (size_t)m0 * D_MODEL + wc * 8;
    const __bf16* Wb = W + (size_t)n0 * D_MODEL + wc * 8;

    v4f acc[4][4] = {};
    GEMM_KLOOP(Ab, Wb)

    const float scale = (z == 0) ? qs : 1.0f;
#pragma unroll
    for (int mt = 0; mt < 4; ++mt)
#pragma unroll
        for (int nt = 0; nt < 4; ++nt) {
            int row = m0 + mw + mt * 16 + qd * 4;
            int col = n0 + nw + nt * 16 + r;
            int bb = row >> 11, l = row & (SEQ - 1);
            int h = col >> 6, d = col & (DKH - 1);
            if (z == 2) {
                v4h o;
#pragma unroll
                for (int i = 0; i < 4; ++i) o[i] = (_Float16)acc[mt][nt][i];
                *(v4h*)&vtb[((size_t)((bb * NHEADS + h) * DKH + d)) * SEQ + l] = o;
            } else {
                __bf16* dst = (z == 0) ? qh : kh;
#pragma unroll
                for (int i = 0; i < 4; ++i)
                    dst[(((size_t)(bb * NHEADS + h) * SEQ) + l + i) * DKH + d] =
                        (__bf16)(acc[mt][nt][i] * scale);
            }
        }
}

// Attention (R6-proven structure): 512 blocks, 4 waves x 64 queries (qa=2 x 32).
// QK: mfma_32x32x16_bf16 -> S[key][query]; P via raw v_exp_f32 + cvt_pkrtz +
// permlane32_swap; PV: mfma_32x32x16_f16 with plain V^T A-frags; psum on VALU.
__global__ __launch_bounds__(256, 2) void attn_kernel(const __bf16* __restrict__ qh,
                                                      const __bf16* __restrict__ kh,
                                                      const _Float16* __restrict__ vt,
                                                      __bf16* __restrict__ oh) {
    const int lane = threadIdx.x & 63, wave = threadIdx.x >> 6;
    const int l31 = lane & 31, hi = lane >> 5, l7 = lane & 7;
    const int id = blockIdx.x;
    const int bh = (id & 7) * 8 + ((id >> 3) & 7); // 8 bh per XCD
    const int q0 = (id >> 6) * 256 + wave * 64;

    __shared__ __align__(16) __bf16 Kb[2][64 * 64];
    __shared__ __align__(16) _Float16 Vb[2][64 * 64];

    const __bf16* kbh = kh + (size_t)bh * SEQ * DKH;
    const _Float16* vbh = vt + (size_t)bh * DKH * SEQ;

    // Q B-frags: query n = q0 + qa*32 + l31, k = c*16 + hi*8 + j
    v8bf qf[2][4];
#pragma unroll
    for (int qa = 0; qa < 2; ++qa)
#pragma unroll
        for (int c = 0; c < 4; ++c)
            qf[qa][c] = *(const v8bf*)&qh[((size_t)bh * SEQ + q0 + qa * 32 + l31) * DKH +
                                          c * 16 + hi * 8];

    v16f oacc[2][2] = {};
    float ps[2] = {0.f, 0.f};
    const v16f dz = {}; // hoisted zero C-operand for QK MFMA chains

    // staging map: wave covers rows wave*16..+15 in 2 passes of 8 rows; 128B rows,
    // dest linear, source chunk XOR-swizzled: LDS chunk p of row rho = src chunk p^(rho&7)
    const int srow = lane >> 3;
    const int sc = (lane & 7) ^ srow;

#pragma unroll
    for (int p = 0; p < 2; ++p) {
        int rb = wave * 16 + p * 8;
        async16(kbh + (size_t)(rb + srow) * DKH + sc * 8, &Kb[0][rb * 64]);
        async16(vbh + (size_t)(rb + srow) * SEQ + sc * 8, &Vb[0][rb * 64]);
    }

    for (int tt = 0; tt < SEQ / 64; ++tt) {
        const int buf = tt & 1;
        __syncthreads(); // buf staged; all waves done reading buf^1
        if (tt + 1 < SEQ / 64) {
            const int t0 = (tt + 1) * 64;
#pragma unroll
            for (int p = 0; p < 2; ++p) {
                int rb = wave * 16 + p * 8;
                async16(kbh + (size_t)(t0 + rb + srow) * DKH + sc * 8, &Kb[buf ^ 1][rb * 64]);
                async16(vbh + (size_t)(rb + srow) * SEQ + t0 + sc * 8, &Vb[buf ^ 1][rb * 64]);
            }
        }
        const __bf16* Kc = Kb[buf];
        const _Float16* Vc = Vb[buf];
#pragma unroll
        for (int kb = 0; kb < 2; ++kb) {
            // K A-frags: m = kb*32 + l31 (key), k = c*16 + hi*8 + j (dk)
            v8bf ka[4];
#pragma unroll
            for (int c = 0; c < 4; ++c)
                ka[c] = *(const v8bf*)&Kc[(kb * 32 + l31) * 64 + (((c * 2 + hi) ^ l7) << 3)];
            v8h pb[2][2]; // [qa][16-key half]
#pragma unroll
            for (int qa = 0; qa < 2; ++qa) {
                v16f d = mfma32x16bf(ka[0], qf[qa][0], dz);
#pragma unroll
                for (int c = 1; c < 4; ++c) d = mfma32x16bf(ka[c], qf[qa][c], d);
                // d reg r = S[key kb*32 + (r&3)+8*(r>>2)+4*hi][query qa*32+l31]
                float e[16];
#pragma unroll
                for (int i = 0; i < 16; ++i) e[i] = fexp2(d[i]);
                ps[qa] += (((e[0] + e[1]) + (e[2] + e[3])) + ((e[4] + e[5]) + (e[6] + e[7]))) +
                          (((e[8] + e[9]) + (e[10] + e[11])) + ((e[12] + e[13]) + (e[14] + e[15])));
#pragma unroll
                for (int kc = 0; kc < 2; ++kc) {
                    // keys kb*32 + kc*16 + {0..15}; own: {0-3,8-11}+4hi, partner: rest
                    unsigned a0 = pkh(e[kc * 8 + 0], e[kc * 8 + 1]); // keys {0,1}+4hi
                    unsigned a1 = pkh(e[kc * 8 + 2], e[kc * 8 + 3]); // keys {2,3}+4hi
                    unsigned b0 = pkh(e[kc * 8 + 4], e[kc * 8 + 5]); // keys {8,9}+4hi
                    unsigned b1 = pkh(e[kc * 8 + 6], e[kc * 8 + 7]); // keys {10,11}+4hi
                    // after swap: a0'=[own lo, partner lo] = k j={0,1}; b0'=k j={4,5}; etc.
                    plswap(a0, b0);
                    plswap(a1, b1);
                    v4u w = {a0, a1, b0, b1};
                    pb[qa][kc] = __builtin_bit_cast(v8h, w);
                }
            }
#pragma unroll
            for (int dg = 0; dg < 2; ++dg)
#pragma unroll
                for (int kc = 0; kc < 2; ++kc) {
                    // V^T A-frag: m = dg*32 + l31 (dk), k = keys kb*32+kc*16+hi*8+j
                    v8h va = *(const v8h*)&Vc[(dg * 32 + l31) * 64 +
                                              (((kb * 4 + kc * 2 + hi) ^ l7) << 3)];
#pragma unroll
                    for (int qa = 0; qa < 2; ++qa)
                        oacc[qa][dg] = mfma32x16h(va, pb[qa][kc], oacc[qa][dg]);
                }
        }
    }

    const int b = bh >> 4, h = bh & (NHEADS - 1);
#pragma unroll
    for (int qa = 0; qa < 2; ++qa) {
        float tot = ps[qa] + __shfl_xor(ps[qa], 32, 64); // partner covers other 16-key halves
        float inv = 1.0f / tot;
        int lq = q0 + qa * 32 + l31;
        __bf16* op = oh + (((size_t)(b * SEQ + lq)) * NHEADS + h) * DKH;
#pragma unroll
        for (int dg = 0; dg < 2; ++dg)
#pragma unroll
            for (int g = 0; g < 4; ++g) {
                // oacc reg 4g+i -> dk = dg*32 + g*8 + hi*4 + i
                v4bf ov;
#pragma unroll
                for (int i = 0; i < 4; ++i) ov[i] = (__bf16)(oacc[qa][dg][g * 4 + i] * inv);
                *(v4bf*)(op + dg * 32 + g * 8 + hi * 4) = ov;
            }
    }
}

extern "C" void kernel_launch(void* const* d_in, const int* in_sizes, int n_in,
                              void* d_out, int out_size, void* d_ws, size_t ws_size,
                              hipStream_t stream) {
    const float* Q = (const float*)d_in[0];
    const float* K = (const float*)d_in[1];
    const float* V = (const float*)d_in[2];
    const float* WQ = (const float*)d_in[3];
    const float* WK = (const float*)d_in[4];
    const float* WV = (const float*)d_in[5];
    const float* WO = (const float*)d_in[6];
    float* out = (float*)d_out;

    const size_t elems = (size_t)M_TOT * D_MODEL;    // 8.4M
    const size_t welems = (size_t)D_MODEL * D_MODEL; // 1.05M
    const size_t fused_need = 8 * welems + 6 * 2 * elems; // bytes: wb(8MB)+6x16MB = 104MB

    dim3 gg(M_TOT / 128, D_MODEL / 128);

    if (ws_size >= fused_need) {
        // Fused path: wb | xq | xk | xv | qh | kh | vtb ; oh aliases xq (dead
        // after gemm_qkv completes; attn writes oh strictly after).
        __bf16* wb = (__bf16*)d_ws;
        __bf16* xq = wb + 4 * welems;
        __bf16* xk = xq + elems;
        __bf16* xv = xk + elems;
        __bf16* qh = xv + elems;
        __bf16* kh = qh + elems;
        _Float16* vtb = (_Float16*)(kh + elems);
        __bf16* oh = xq; // alias

        cvt_all<<<14336, 256, 0, stream>>>(Q, K, V, WQ, WK, WV, WO, xq, xk, xv, wb);
        dim3 gz(M_TOT / 128, D_MODEL / 128, 3);
        gemm_qkv<<<gz, 256, 0, stream>>>(xq, xk, xv, wb, qh, kh, vtb, 0.125f * LOG2E);
        attn_kernel<<<512, 256, 0, stream>>>(qh, kh, vtb, oh);
        gemm_nt<0><<<gg, 256, 0, stream>>>(oh, wb + 3 * welems, out, 1.0f);
    } else {
        // Serial fallback (88 MB).
        __bf16* wb = (__bf16*)d_ws;
        __bf16* xb = wb + 4 * welems;
        __bf16* qh = xb + elems;
        __bf16* kh = qh + elems;
        _Float16* vtb = (_Float16*)(kh + elems);
        __bf16* oh = (__bf16*)(vtb + elems);

        cvt_w<<<2048, 256, 0, stream>>>(WQ, WK, WV, WO, wb);
        cvt_x<<<4096, 256, 0, stream>>>(Q, xb);
        gemm_nt<1><<<gg, 256, 0, stream>>>(xb, wb, qh, 0.125f * LOG2E);
        cvt_x<<<4096, 256, 0, stream>>>(K, xb);
        gemm_nt<1><<<gg, 256, 0, stream>>>(xb, wb + welems, kh, 1.0f);
        cvt_x<<<4096, 256, 0, stream>>>(V, xb);
        gemm_nt<2><<<gg, 256, 0, stream>>>(xb, wb + 2 * welems, vtb, 1.0f);
        attn_kernel<<<512, 256, 0, stream>>>(qh, kh, vtb, oh);
        gemm_nt<0><<<gg, 256, 0, stream>>>(oh, wb + 3 * welems, out, 1.0f);
    }
}